// Round 6
// baseline (1343.267 us; speedup 1.0000x reference)
//
#include <hip/hip_runtime.h>
#include <hip/hip_fp16.h>
#include <math.h>

#define NN 50000
#define EE 800000
#define HIDDEN 128
#define NGRAPH 50

struct __align__(8) kv8 { __half2 k2, v2; };

// ---------------- CSR build ----------------
__global__ void k_deg(const int* __restrict__ eidx, int* __restrict__ cnt) {
    int e = blockIdx.x * blockDim.x + threadIdx.x;
    if (e < EE) atomicAdd(&cnt[eidx[EE + e]], 1);
}

// scan + housekeeping: exclusive-scan deg->row_ptr, zero cnt (scatter cursor),
// zero bn_acc3 / gsum / gcnt (removes 4 memset launches)
__global__ void k_scan(int* __restrict__ cnt, int* __restrict__ row_ptr,
                       float* __restrict__ bn_acc3, float* __restrict__ gsum,
                       int* __restrict__ gcnt) {
    __shared__ int wsum[16];
    __shared__ int carry_s;
    int t = threadIdx.x;
    int lane = t & 63, w = t >> 6;
    if (t < 768) bn_acc3[t] = 0.f;
    if (t < 64) { gsum[t] = 0.f; gcnt[t] = 0; }
    if (t == 0) carry_s = 0;
    __syncthreads();
    for (int base = 0; base < NN; base += 1024) {
        int i = base + t;
        int v = (i < NN) ? cnt[i] : 0;
        int s = v;
#pragma unroll
        for (int o = 1; o < 64; o <<= 1) {
            int u = __shfl_up(s, o);
            if (lane >= o) s += u;
        }
        if (lane == 63) wsum[w] = s;
        __syncthreads();
        if (w == 0) {
            int ws = (lane < 16) ? wsum[lane] : 0;
#pragma unroll
            for (int o = 1; o < 16; o <<= 1) {
                int u = __shfl_up(ws, o);
                if (lane >= o) ws += u;
            }
            if (lane < 16) wsum[lane] = ws;
        }
        __syncthreads();
        int wpre = (w == 0) ? 0 : wsum[w - 1];
        int carry = carry_s;
        if (i < NN) { row_ptr[i] = carry + wpre + s - v; cnt[i] = 0; }
        __syncthreads();
        if (t == 1023) carry_s = carry + wpre + s;
        __syncthreads();
    }
    if (t == 0) row_ptr[NN] = carry_s;
}

// scatter: build CSR-ordered src-index and edge-attr arrays
__global__ void k_scatter(const int* __restrict__ eidx, const float* __restrict__ eattr,
                          const int* __restrict__ row_ptr,
                          int* __restrict__ cur, int* __restrict__ esrc, float* __restrict__ eat2) {
    int e = blockIdx.x * blockDim.x + threadIdx.x;
    if (e < EE) {
        int d = eidx[EE + e];
        int s = eidx[e];
        int p = atomicAdd(&cur[d], 1);
        int pos = row_ptr[d] + p;
        esrc[pos] = s;
        float2 ea = *(const float2*)&eattr[2 * (size_t)e];
        *(float2*)&eat2[2 * (size_t)pos] = ea;
    }
}

// ---- fused 4-way GEMM: q,xr fp32; k,v packed fp16 interleaved.
// When use_ab: BN affine+ELU applied to input X, computed in-block from bn_acc stats.
__global__ __launch_bounds__(256) void k_gemm4(
    const float* __restrict__ X,
    const float* __restrict__ Wq, const float* __restrict__ bq,
    const float* __restrict__ Wk, const float* __restrict__ bk,
    const float* __restrict__ Wv, const float* __restrict__ bv,
    const float* __restrict__ Ws, const float* __restrict__ bs,
    const float* __restrict__ bn_acc, const float* __restrict__ gamma,
    const float* __restrict__ beta, int use_ab,
    float* __restrict__ qo, __half* __restrict__ kvh, float* __restrict__ xro)
{
    __shared__ float xs[64][132];
    __shared__ float ab_s[256];
    int t = threadIdx.x;
    int m0 = blockIdx.x * 64;
    if (use_ab) {
        if (t < 128) {
            float mu = bn_acc[t] * (1.f / NN);
            float var = bn_acc[128 + t] * (1.f / NN) - mu * mu;
            float inv = rsqrtf(var + 1e-5f);
            float a = inv * gamma[t];
            ab_s[t] = a;
            ab_s[128 + t] = beta[t] - mu * a;
        }
        __syncthreads();
    }
#pragma unroll
    for (int i = 0; i < 8; ++i) {
        int f = t + 256 * i;          // float4 index within 64x32
        int r = f >> 5, c4 = (f & 31) << 2;
        float4 val = make_float4(0.f, 0.f, 0.f, 0.f);
        if (m0 + r < NN) val = *(const float4*)&X[(size_t)(m0 + r) * 128 + c4];
        if (use_ab) {
            float4 a = *(const float4*)&ab_s[c4];
            float4 bb = *(const float4*)&ab_s[128 + c4];
            float z;
            z = fmaf(val.x, a.x, bb.x); val.x = z > 0.f ? z : expm1f(z);
            z = fmaf(val.y, a.y, bb.y); val.y = z > 0.f ? z : expm1f(z);
            z = fmaf(val.z, a.z, bb.z); val.z = z > 0.f ? z : expm1f(z);
            z = fmaf(val.w, a.w, bb.w); val.w = z > 0.f ? z : expm1f(z);
        }
        *(float4*)&xs[r][c4] = val;
    }
    __syncthreads();
    int cg = t & 15, ng = t >> 4;
    int c0 = cg * 8;
    int mb = ng * 4;
    const float* Wm[4] = {Wq, Wk, Wv, Ws};
    const float* bm[4] = {bq, bk, bv, bs};
    __half2 khold[4][4];
#pragma unroll
    for (int w = 0; w < 4; ++w) {
        const float* __restrict__ W = Wm[w];
        float acc[4][8];
#pragma unroll
        for (int i = 0; i < 4; i++)
#pragma unroll
            for (int j = 0; j < 8; j++) acc[i][j] = 0.f;
        for (int k = 0; k < 128; k += 4) {
            float4 xa[4];
#pragma unroll
            for (int i = 0; i < 4; i++) xa[i] = *(const float4*)&xs[mb + i][k];
            float4 wr[4][2];
#pragma unroll
            for (int kk = 0; kk < 4; kk++) {
                wr[kk][0] = *(const float4*)&W[(k + kk) * 128 + c0];
                wr[kk][1] = *(const float4*)&W[(k + kk) * 128 + c0 + 4];
            }
#pragma unroll
            for (int kk = 0; kk < 4; kk++) {
                float wv[8] = {wr[kk][0].x, wr[kk][0].y, wr[kk][0].z, wr[kk][0].w,
                               wr[kk][1].x, wr[kk][1].y, wr[kk][1].z, wr[kk][1].w};
#pragma unroll
                for (int i = 0; i < 4; i++) {
                    float xv = ((const float*)&xa[i])[kk];
#pragma unroll
                    for (int j = 0; j < 8; j++) acc[i][j] = fmaf(xv, wv[j], acc[i][j]);
                }
            }
        }
        float bb[8];
        *(float4*)&bb[0] = *(const float4*)&bm[w][c0];
        *(float4*)&bb[4] = *(const float4*)&bm[w][c0 + 4];
        if (w == 0 || w == 3) {
            float* om = (w == 0) ? qo : xro;
#pragma unroll
            for (int i = 0; i < 4; i++) {
                int node = m0 + mb + i;
                if (node < NN) {
                    float4 o0 = make_float4(acc[i][0] + bb[0], acc[i][1] + bb[1],
                                            acc[i][2] + bb[2], acc[i][3] + bb[3]);
                    float4 o1 = make_float4(acc[i][4] + bb[4], acc[i][5] + bb[5],
                                            acc[i][6] + bb[6], acc[i][7] + bb[7]);
                    *(float4*)&om[(size_t)node * 128 + c0] = o0;
                    *(float4*)&om[(size_t)node * 128 + c0 + 4] = o1;
                }
            }
        } else if (w == 1) {
#pragma unroll
            for (int i = 0; i < 4; i++)
#pragma unroll
                for (int j = 0; j < 4; j++)
                    khold[i][j] = __float22half2_rn(
                        make_float2(acc[i][2 * j] + bb[2 * j], acc[i][2 * j + 1] + bb[2 * j + 1]));
        } else {  // w == 2: interleaved {k0,k1,v0,v1} per channel pair
#pragma unroll
            for (int i = 0; i < 4; i++) {
                int node = m0 + mb + i;
                if (node < NN) {
#pragma unroll
                    for (int j = 0; j < 4; j++) {
                        kv8 p;
                        p.k2 = khold[i][j];
                        p.v2 = __float22half2_rn(
                            make_float2(acc[i][2 * j] + bb[2 * j], acc[i][2 * j + 1] + bb[2 * j + 1]));
                        *(kv8*)&kvh[(size_t)node * 256 + 2 * c0 + 4 * j] = p;
                    }
                }
            }
        }
    }
}

// ---------------- attention + gate + BN-stats (one wave per dst node) ----------------
// 16 kv gathers in flight per group; edge-embedding decomposed into per-head scalars:
//   alpha = q.k + cx*ea.x + cy*ea.y + cb ;  out = (sum w*v + Sx*We_x + Sy*We_y + den*be)/den
__global__ __launch_bounds__(256) void k_attn(
    const float* __restrict__ q, const __half* __restrict__ kvh,
    const float* __restrict__ xr,
    const int* __restrict__ esrc, const float* __restrict__ eat2,
    const int* __restrict__ row_ptr,
    const float* __restrict__ We, const float* __restrict__ be,
    const float* __restrict__ Wb,
    float* __restrict__ out2, float* __restrict__ bn_accum)
{
    int t = threadIdx.x;
    int lane = t & 63;
    int wid = t >> 6;
    int gwave = blockIdx.x * 4 + wid;
    int nwaves = gridDim.x * 4;
    int ch = lane * 2;
    size_t lane8 = 4 * lane;           // half offset within a node's 256-half kv row
    float2 we0 = *(const float2*)&We[ch];
    float2 we1 = *(const float2*)&We[128 + ch];
    float2 beL = *(const float2*)&be[ch];
    float2 wb_o = *(const float2*)&Wb[ch];
    float2 wb_r = *(const float2*)&Wb[128 + ch];
    float2 wb_d = *(const float2*)&Wb[256 + ch];
    const float eta = 0.17677669529663687f * 1.4426950408889634f;  // (1/sqrt(32))*log2(e)
    float bnsx = 0.f, bnsy = 0.f, bnqx = 0.f, bnqy = 0.f;

    for (int n = gwave; n < NN; n += nwaves) {
        int rs = __builtin_amdgcn_readfirstlane(row_ptr[n]);
        int re = __builtin_amdgcn_readfirstlane(row_ptr[n + 1]);
        float2 qv = *(const float2*)&q[(size_t)n * 128 + ch];
        float2 qs = make_float2(qv.x * eta, qv.y * eta);
        // per-head scalars for the edge-embedding contribution (reduce over 16 lanes)
        float cx = qs.x * we0.x + qs.y * we0.y;
        float cy = qs.x * we1.x + qs.y * we1.y;
        float cb_ = qs.x * beL.x + qs.y * beL.y;
#pragma unroll
        for (int o = 1; o < 16; o <<= 1) {
            cx += __shfl_xor(cx, o);
            cy += __shfl_xor(cy, o);
            cb_ += __shfl_xor(cb_, o);
        }
        float den = 0.f, Sx = 0.f, Sy = 0.f, ax = 0.f, ay = 0.f;

        for (int cbase = rs; cbase < re; cbase += 64) {
            int cnum = re - cbase; if (cnum > 64) cnum = 64;
            int mi = cbase + lane;
            int sv = 0;
            float2 av = make_float2(0.f, 0.f);
            if (mi < re) {
                sv = esrc[mi];
                av = *(const float2*)&eat2[2 * (size_t)mi];
            }
            for (int base = 0; base < cnum; base += 16) {
                int m = cnum - base; if (m > 16) m = 16;
                kv8 kk[16];
#pragma unroll
                for (int j = 0; j < 16; j++) {
                    int s = __shfl(sv, base + j);
                    kk[j] = *(const kv8*)&kvh[(size_t)s * 256 + lane8];
                }
#pragma unroll
                for (int j = 0; j < 16; j++) {
                    float eax = __shfl(av.x, base + j);
                    float eay = __shfl(av.y, base + j);
                    float2 kf = __half22float2(kk[j].k2);
                    float2 vf = __half22float2(kk[j].v2);
                    float p = qs.x * kf.x + qs.y * kf.y;
                    p += __shfl_xor(p, 1);
                    p += __shfl_xor(p, 2);
                    p += __shfl_xor(p, 4);
                    p += __shfl_xor(p, 8);
                    float alpha = p + fmaf(cx, eax, fmaf(cy, eay, cb_));
                    alpha = (j < m) ? alpha : -1.0e30f;
                    float exv = exp2f(alpha);
                    den += exv;
                    Sx = fmaf(exv, eax, Sx);
                    Sy = fmaf(exv, eay, Sy);
                    ax = fmaf(exv, vf.x, ax);
                    ay = fmaf(exv, vf.y, ay);
                }
            }
        }
        float rden = 1.f / (den + 1e-16f);
        float axn = (ax + Sx * we0.x + Sy * we1.x + den * beL.x) * rden;
        float ayn = (ay + Sx * we0.y + Sy * we1.y + den * beL.y) * rden;
        // beta gate
        float2 xv = *(const float2*)&xr[(size_t)n * 128 + ch];
        float gp = axn * wb_o.x + ayn * wb_o.y + xv.x * wb_r.x + xv.y * wb_r.y
                 + (axn - xv.x) * wb_d.x + (ayn - xv.y) * wb_d.y;
        gp += __shfl_xor(gp, 1);
        gp += __shfl_xor(gp, 2);
        gp += __shfl_xor(gp, 4);
        gp += __shfl_xor(gp, 8);
        gp += __shfl_xor(gp, 16);
        gp += __shfl_xor(gp, 32);
        float gate = 1.f / (1.f + __expf(-gp));
        float ox = gate * xv.x + (1.f - gate) * axn;
        float oy = gate * xv.y + (1.f - gate) * ayn;
        *(float2*)&out2[(size_t)n * 128 + ch] = make_float2(ox, oy);
        bnsx += ox; bnsy += oy;
        bnqx = fmaf(ox, ox, bnqx); bnqy = fmaf(oy, oy, bnqy);
    }
    // block-level BN partial reduce
    __shared__ float s_sum[2][256], s_sq[2][256];
    s_sum[0][t] = bnsx; s_sum[1][t] = bnsy;
    s_sq[0][t] = bnqx;  s_sq[1][t] = bnqy;
    __syncthreads();
    if (t < 64) {
        float sx = s_sum[0][t] + s_sum[0][64 + t] + s_sum[0][128 + t] + s_sum[0][192 + t];
        float sy = s_sum[1][t] + s_sum[1][64 + t] + s_sum[1][128 + t] + s_sum[1][192 + t];
        float qx = s_sq[0][t] + s_sq[0][64 + t] + s_sq[0][128 + t] + s_sq[0][192 + t];
        float qy = s_sq[1][t] + s_sq[1][64 + t] + s_sq[1][128 + t] + s_sq[1][192 + t];
        int c = 2 * t;
        atomicAdd(&bn_accum[c], sx);
        atomicAdd(&bn_accum[c + 1], sy);
        atomicAdd(&bn_accum[128 + c], qx);
        atomicAdd(&bn_accum[128 + c + 1], qy);
    }
}

// ------- readout: BN affine+ELU+dot(Wout), LDS per-graph accumulate, one flush per block -------
__global__ __launch_bounds__(256) void k_pool(const float* __restrict__ x,
                                              const float* __restrict__ bn_acc,
                                              const float* __restrict__ gamma,
                                              const float* __restrict__ beta,
                                              const float* __restrict__ Wout,
                                              const int* __restrict__ batch,
                                              float* __restrict__ gsum, int* __restrict__ gcnt) {
    __shared__ float lsum[NGRAPH];
    __shared__ int lcnt[NGRAPH];
    __shared__ float ab_s[256];
    int t = threadIdx.x;
    if (t < NGRAPH) { lsum[t] = 0.f; lcnt[t] = 0; }
    if (t < 128) {
        float mu = bn_acc[t] * (1.f / NN);
        float var = bn_acc[128 + t] * (1.f / NN) - mu * mu;
        float inv = rsqrtf(var + 1e-5f);
        float a = inv * gamma[t];
        ab_s[t] = a;
        ab_s[128 + t] = beta[t] - mu * a;
    }
    __syncthreads();
    int lane = t & 63;
    int wid = t >> 6;
    int ch = lane * 2;
    float2 wo = *(const float2*)&Wout[ch];
    float2 a = *(const float2*)&ab_s[ch];
    float2 b = *(const float2*)&ab_s[128 + ch];
    int base = blockIdx.x * 16 + wid * 4;
#pragma unroll
    for (int i = 0; i < 4; i++) {
        int n = base + i;
        if (n < NN) {
            float2 xv = *(const float2*)&x[(size_t)n * 128 + ch];
            float z0 = fmaf(xv.x, a.x, b.x); z0 = z0 > 0.f ? z0 : expm1f(z0);
            float z1 = fmaf(xv.y, a.y, b.y); z1 = z1 > 0.f ? z1 : expm1f(z1);
            float p = z0 * wo.x + z1 * wo.y;
            p += __shfl_xor(p, 1);
            p += __shfl_xor(p, 2);
            p += __shfl_xor(p, 4);
            p += __shfl_xor(p, 8);
            p += __shfl_xor(p, 16);
            p += __shfl_xor(p, 32);
            if (lane == 0) {
                int g = batch[n];
                atomicAdd(&lsum[g], p);
                atomicAdd(&lcnt[g], 1);
            }
        }
    }
    __syncthreads();
    if (t < NGRAPH && lcnt[t] > 0) {
        atomicAdd(&gsum[t], lsum[t]);
        atomicAdd(&gcnt[t], lcnt[t]);
    }
}

__global__ void k_final(const float* __restrict__ gsum, const int* __restrict__ gcnt,
                        const float* __restrict__ bout, const float* __restrict__ obias,
                        float* __restrict__ out) {
    int g = threadIdx.x;
    if (g < NGRAPH) out[g] = gsum[g] / fmaxf((float)gcnt[g], 1.f) + bout[0] + obias[0];
}

extern "C" void kernel_launch(void* const* d_in, const int* in_sizes, int n_in,
                              void* d_out, int out_size, void* d_ws, size_t ws_size,
                              hipStream_t stream) {
    const float* x_in       = (const float*)d_in[0];
    const int* eidx         = (const int*)d_in[1];
    const float* eattr      = (const float*)d_in[2];
    const int* batch        = (const int*)d_in[3];
    const float* Wq         = (const float*)d_in[4];
    const float* bq         = (const float*)d_in[5];
    const float* Wk         = (const float*)d_in[6];
    const float* bk         = (const float*)d_in[7];
    const float* Wv         = (const float*)d_in[8];
    const float* bv         = (const float*)d_in[9];
    const float* We         = (const float*)d_in[10];
    const float* be         = (const float*)d_in[11];
    const float* Wskip      = (const float*)d_in[12];
    const float* bskip      = (const float*)d_in[13];
    const float* Wbeta      = (const float*)d_in[14];
    const float* bn_gamma   = (const float*)d_in[15];
    const float* bn_beta    = (const float*)d_in[16];
    const float* Wout       = (const float*)d_in[17];
    const float* bout       = (const float*)d_in[18];
    const float* obias      = (const float*)d_in[19];
    float* out = (float*)d_out;

    char* ws = (char*)d_ws;
    size_t off = 0;
    auto alloc = [&](size_t bytes) -> void* {
        off = (off + 255) & ~(size_t)255;
        void* p = ws + off;
        off += bytes;
        return p;
    };
    const size_t NF = (size_t)NN * 128 * sizeof(float);
    float* xbuf    = (float*)alloc(NF);
    float* qb      = (float*)alloc(NF);
    float* xrb     = (float*)alloc(NF);
    __half* kvh    = (__half*)alloc((size_t)NN * 256 * sizeof(__half));
    int* row_ptr   = (int*)alloc((NN + 1) * sizeof(int));
    int* cnt       = (int*)alloc(NN * sizeof(int));
    int* esrc      = (int*)alloc(EE * sizeof(int));
    float* eat2    = (float*)alloc((size_t)EE * 2 * sizeof(float));
    float* bn_acc3 = (float*)alloc(3 * 256 * sizeof(float));
    float* gsum    = (float*)alloc(64 * sizeof(float));
    int* gcnt      = (int*)alloc(64 * sizeof(int));
    (void)ws_size; (void)n_in; (void)in_sizes; (void)out_size;

    // ---- CSR build (dst -> src, eattr reordered) + zero aux buffers ----
    hipMemsetAsync(cnt, 0, NN * sizeof(int), stream);
    k_deg<<<(EE + 255) / 256, 256, 0, stream>>>(eidx, cnt);
    k_scan<<<1, 1024, 0, stream>>>(cnt, row_ptr, bn_acc3, gsum, gcnt);
    k_scatter<<<(EE + 255) / 256, 256, 0, stream>>>(eidx, eattr, row_ptr, cnt, esrc, eat2);

    // ---- layers ----
    for (int l = 0; l < 3; ++l) {
        const float* Xl = (l == 0) ? x_in : xbuf;
        const float* prev_acc = (l == 0) ? bn_acc3 : bn_acc3 + (l - 1) * 256;
        k_gemm4<<<(NN + 63) / 64, 256, 0, stream>>>(
            Xl,
            Wq + (size_t)l * 16384, bq + l * 128,
            Wk + (size_t)l * 16384, bk + l * 128,
            Wv + (size_t)l * 16384, bv + l * 128,
            Wskip + (size_t)l * 16384, bskip + l * 128,
            prev_acc, bn_gamma + (l == 0 ? 0 : (l - 1) * 128),
            bn_beta + (l == 0 ? 0 : (l - 1) * 128), (l == 0) ? 0 : 1,
            qb, kvh, xrb);
        k_attn<<<3125, 256, 0, stream>>>(
            qb, kvh, xrb, esrc, eat2, row_ptr,
            We + (size_t)l * 256, be + l * 128, Wbeta + (size_t)l * 384,
            xbuf, bn_acc3 + l * 256);
    }

    // ---- readout (BN affine+ELU of layer-2 fused in) ----
    k_pool<<<(NN + 15) / 16, 256, 0, stream>>>(xbuf, bn_acc3 + 2 * 256,
                                               bn_gamma + 2 * 128, bn_beta + 2 * 128,
                                               Wout, batch, gsum, gcnt);
    k_final<<<1, 64, 0, stream>>>(gsum, gcnt, bout, obias, out);
}